// Round 1
// baseline (1354.818 us; speedup 1.0000x reference)
//
#include <hip/hip_runtime.h>
#include <hip/hip_bf16.h>
#include <math.h>

#define B_   2
#define L_   2048
#define D_   2048
#define H_   16
#define DH_  128
#define DFF_ 8192
#define NTOK (B_*L_)

typedef __attribute__((ext_vector_type(8))) short bf16x8;
typedef __attribute__((ext_vector_type(4))) float floatx4;
typedef unsigned short u16;

__device__ __forceinline__ u16 f2bf(float f) {
    union { float f; unsigned u; } c; c.f = f;
    unsigned r = (c.u + 0x7fffu + ((c.u >> 16) & 1u)) >> 16;
    return (u16)r;
}

// ---------------- fp32 -> bf16 convert ----------------
__global__ __launch_bounds__(256) void cvt_bf16(const float* __restrict__ in,
                                                u16* __restrict__ out, int n4) {
    int i = blockIdx.x * 256 + threadIdx.x;
    if (i >= n4) return;
    float4 v = ((const float4*)in)[i];
    ushort4 o = { f2bf(v.x), f2bf(v.y), f2bf(v.z), f2bf(v.w) };
    ((ushort4*)out)[i] = o;
}

// ---------------- RMSNorm: fp32 in -> bf16 out ----------------
__global__ __launch_bounds__(256) void rmsnorm_kernel(const float* __restrict__ x,
                                                      const float* __restrict__ w,
                                                      u16* __restrict__ out) {
    const int row = blockIdx.x, tid = threadIdx.x;
    const float* xr = x + (size_t)row * D_;
    float4 a = ((const float4*)xr)[tid];
    float4 b = ((const float4*)xr)[tid + 256];
    float ss = a.x*a.x + a.y*a.y + a.z*a.z + a.w*a.w
             + b.x*b.x + b.y*b.y + b.z*b.z + b.w*b.w;
#pragma unroll
    for (int d = 1; d < 64; d <<= 1) ss += __shfl_xor(ss, d, 64);
    __shared__ float sred[4];
    if ((tid & 63) == 0) sred[tid >> 6] = ss;
    __syncthreads();
    float tot = sred[0] + sred[1] + sred[2] + sred[3];
    float inv = 1.0f / sqrtf(tot * (1.0f / D_) + 1e-8f);
    float4 w0 = ((const float4*)w)[tid];
    float4 w1 = ((const float4*)w)[tid + 256];
    ushort4 o0 = { f2bf(a.x*inv*w0.x), f2bf(a.y*inv*w0.y), f2bf(a.z*inv*w0.z), f2bf(a.w*inv*w0.w) };
    ushort4 o1 = { f2bf(b.x*inv*w1.x), f2bf(b.y*inv*w1.y), f2bf(b.z*inv*w1.z), f2bf(b.w*inv*w1.w) };
    ushort4* orow = (ushort4*)(out + (size_t)row * D_);
    orow[tid] = o0;
    orow[tid + 256] = o1;
}

// ---------------- GEMM: C[M,N] = A[M,K] * W[N,K]^T, bf16 in, fp32 acc ----------------
// MODE 0: out bf16 in [B,H,L,DH] layout, scaled (QKV projections)
// MODE 1: out fp32 = acc + residual[m*N+n]
// MODE 2: out bf16 row-major with exact-erf GELU applied
template<int MODE>
__global__ __launch_bounds__(256) void gemm_bt(const u16* __restrict__ A,
                                               const u16* __restrict__ Bw,
                                               void* __restrict__ outp,
                                               const float* __restrict__ residual,
                                               int M, int N, int K, float scale) {
    __shared__ __attribute__((aligned(16))) u16 lds_a[128 * 32];
    __shared__ __attribute__((aligned(16))) u16 lds_b[128 * 32];
    const int tid = threadIdx.x;
    const int wave = tid >> 6, lane = tid & 63;
    const int qd = lane >> 4, c16 = lane & 15;
    const int wm = (wave >> 1) * 64, wn = (wave & 1) * 64;
    const long tile_m = (long)blockIdx.y * 128, tile_n = (long)blockIdx.x * 128;

    floatx4 acc[4][4] = {};

    const int r0 = tid >> 2;            // 0..63
    const int r1 = r0 + 64;             // 64..127
    const int kc = (tid & 3) * 8;       // 0,8,16,24
    const u16* a0 = A + (tile_m + r0) * (long)K + kc;
    const u16* a1 = A + (tile_m + r1) * (long)K + kc;
    const u16* b0 = Bw + (tile_n + r0) * (long)K + kc;
    const u16* b1 = Bw + (tile_n + r1) * (long)K + kc;

    for (int k0 = 0; k0 < K; k0 += 32) {
        *(int4*)&lds_a[r0 * 32 + kc] = *(const int4*)(a0 + k0);
        *(int4*)&lds_a[r1 * 32 + kc] = *(const int4*)(a1 + k0);
        *(int4*)&lds_b[r0 * 32 + kc] = *(const int4*)(b0 + k0);
        *(int4*)&lds_b[r1 * 32 + kc] = *(const int4*)(b1 + k0);
        __syncthreads();
        bf16x8 af[4], bv[4];
#pragma unroll
        for (int i = 0; i < 4; i++)
            af[i] = *(const bf16x8*)&lds_a[(wm + i * 16 + c16) * 32 + qd * 8];
#pragma unroll
        for (int j = 0; j < 4; j++)
            bv[j] = *(const bf16x8*)&lds_b[(wn + j * 16 + c16) * 32 + qd * 8];
#pragma unroll
        for (int i = 0; i < 4; i++)
#pragma unroll
            for (int j = 0; j < 4; j++)
                acc[i][j] = __builtin_amdgcn_mfma_f32_16x16x32_bf16(af[i], bv[j], acc[i][j], 0, 0, 0);
        __syncthreads();
    }

#pragma unroll
    for (int i = 0; i < 4; i++) {
#pragma unroll
        for (int j = 0; j < 4; j++) {
#pragma unroll
            for (int r = 0; r < 4; r++) {
                long m = tile_m + wm + i * 16 + qd * 4 + r;
                long n = tile_n + wn + j * 16 + c16;
                float v = acc[i][j][r];
                if (MODE == 0) {
                    long b = m >> 11, l = m & 2047;   // L_ = 2048
                    long h = n >> 7, dh = n & 127;    // DH_ = 128
                    ((u16*)outp)[((b * H_ + h) * (long)L_ + l) * DH_ + dh] = f2bf(v * scale);
                } else if (MODE == 1) {
                    long idx = m * (long)N + n;
                    ((float*)outp)[idx] = v + residual[idx];
                } else {
                    float g = 0.5f * v * (1.0f + erff(v * 0.70710678118654752f));
                    ((u16*)outp)[m * (long)N + n] = f2bf(g);
                }
            }
        }
    }
}

// ---------------- Flash-style causal attention ----------------
// grid: (L/64 q-tiles, B*H heads), block 256 = 4 waves, 16 Q rows per wave.
__global__ __launch_bounds__(256) void attn_kernel(const u16* __restrict__ Q,
                                                   const u16* __restrict__ K,
                                                   const u16* __restrict__ V,
                                                   u16* __restrict__ O) {
    __shared__ __attribute__((aligned(16))) u16 kt_lds[64 * 128];   // K tile [kv][dh]
    __shared__ __attribute__((aligned(16))) u16 vt_lds[128 * 64];   // V^T  [dh][kv]
    __shared__ __attribute__((aligned(16))) u16 p_lds[4][16 * 64];  // per-wave P
    const int tid = threadIdx.x;
    const int wave = tid >> 6, lane = tid & 63;
    const int qd = lane >> 4, c16 = lane & 15;
    const int qt = blockIdx.x, bh = blockIdx.y;
    const u16* qh = Q + (size_t)bh * L_ * DH_;
    const u16* kh = K + (size_t)bh * L_ * DH_;
    const u16* vh = V + (size_t)bh * L_ * DH_;
    const int q0 = qt * 64;

    bf16x8 qf[4];
#pragma unroll
    for (int s = 0; s < 4; s++)
        qf[s] = *(const bf16x8*)(qh + (size_t)(q0 + wave * 16 + c16) * DH_ + s * 32 + qd * 8);

    floatx4 o_acc[8] = {};
    float m_i[4], l_i[4];
#pragma unroll
    for (int r = 0; r < 4; r++) { m_i[r] = -1e30f; l_i[r] = 0.f; }

    for (int kt = 0; kt <= qt; kt++) {
        const int kv0 = kt * 64;
#pragma unroll
        for (int s = 0; s < 4; s++) {
            int c = tid + s * 256;
            int r = c >> 4, off = (c & 15) * 8;
            *(int4*)&kt_lds[r * 128 + off] = *(const int4*)(kh + (size_t)(kv0 + r) * DH_ + off);
            bf16x8 vv = *(const bf16x8*)(vh + (size_t)(kv0 + r) * DH_ + off);
#pragma unroll
            for (int e = 0; e < 8; e++)
                vt_lds[(off + e) * 64 + r] = (u16)vv[e];
        }
        __syncthreads();

        floatx4 s_acc[4] = {};
#pragma unroll
        for (int j = 0; j < 4; j++)
#pragma unroll
            for (int s = 0; s < 4; s++) {
                bf16x8 kf = *(const bf16x8*)&kt_lds[(j * 16 + c16) * 128 + s * 32 + qd * 8];
                s_acc[j] = __builtin_amdgcn_mfma_f32_16x16x32_bf16(qf[s], kf, s_acc[j], 0, 0, 0);
            }

        if (kt == qt) {
#pragma unroll
            for (int j = 0; j < 4; j++)
#pragma unroll
                for (int r = 0; r < 4; r++) {
                    int col = j * 16 + c16;
                    int row = wave * 16 + qd * 4 + r;
                    if (col > row) s_acc[j][r] = -1e30f;
                }
        }

        float rmax[4], rsum[4], alpha[4];
#pragma unroll
        for (int r = 0; r < 4; r++) {
            float mx = fmaxf(fmaxf(s_acc[0][r], s_acc[1][r]), fmaxf(s_acc[2][r], s_acc[3][r]));
#pragma unroll
            for (int d = 1; d < 16; d <<= 1) mx = fmaxf(mx, __shfl_xor(mx, d, 64));
            float mnew = fmaxf(m_i[r], mx);
            alpha[r] = __expf(m_i[r] - mnew);
            m_i[r] = mnew;
            rsum[r] = 0.f;
        }
#pragma unroll
        for (int j = 0; j < 4; j++)
#pragma unroll
            for (int r = 0; r < 4; r++) {
                float p = __expf(s_acc[j][r] - m_i[r]);
                s_acc[j][r] = p;
                rsum[r] += p;
            }
#pragma unroll
        for (int r = 0; r < 4; r++) {
#pragma unroll
            for (int d = 1; d < 16; d <<= 1) rsum[r] += __shfl_xor(rsum[r], d, 64);
            l_i[r] = l_i[r] * alpha[r] + rsum[r];
        }
#pragma unroll
        for (int j8 = 0; j8 < 8; j8++)
#pragma unroll
            for (int r = 0; r < 4; r++) o_acc[j8][r] *= alpha[r];

        // P: C-layout -> LDS -> A-layout (per-wave private region)
#pragma unroll
        for (int j = 0; j < 4; j++)
#pragma unroll
            for (int r = 0; r < 4; r++)
                p_lds[wave][(qd * 4 + r) * 64 + j * 16 + c16] = f2bf(s_acc[j][r]);

#pragma unroll
        for (int s = 0; s < 2; s++) {
            bf16x8 pf = *(const bf16x8*)&p_lds[wave][c16 * 64 + s * 32 + qd * 8];
#pragma unroll
            for (int j8 = 0; j8 < 8; j8++) {
                bf16x8 vf = *(const bf16x8*)&vt_lds[(j8 * 16 + c16) * 64 + s * 32 + qd * 8];
                o_acc[j8] = __builtin_amdgcn_mfma_f32_16x16x32_bf16(pf, vf, o_acc[j8], 0, 0, 0);
            }
        }
        __syncthreads();
    }

    const int b = bh >> 4, h = bh & 15;
    float inv_l[4];
#pragma unroll
    for (int r = 0; r < 4; r++) inv_l[r] = 1.0f / l_i[r];
#pragma unroll
    for (int j8 = 0; j8 < 8; j8++)
#pragma unroll
        for (int r = 0; r < 4; r++) {
            int l = q0 + wave * 16 + qd * 4 + r;
            int d = h * DH_ + j8 * 16 + c16;
            O[(size_t)(b * L_ + l) * D_ + d] = f2bf(o_acc[j8][r] * inv_l[r]);
        }
}

// ---------------- launch ----------------
extern "C" void kernel_launch(void* const* d_in, const int* in_sizes, int n_in,
                              void* d_out, int out_size, void* d_ws, size_t ws_size,
                              hipStream_t stream) {
    const float* x     = (const float*)d_in[0];
    const float* ln1_w = (const float*)d_in[2];
    const float* wq    = (const float*)d_in[3];
    const float* wk    = (const float*)d_in[4];
    const float* wv    = (const float*)d_in[5];
    const float* wo    = (const float*)d_in[6];
    const float* ln2_w = (const float*)d_in[7];
    const float* w_up  = (const float*)d_in[8];
    const float* w_dn  = (const float*)d_in[9];

    char* ws = (char*)d_ws;
    const size_t MB = 1024 * 1024;
    // arena (144 MB total, phase-aliased):
    float* x2   = (float*)(ws + 0);          // 32 MB, live to end
    u16* hbuf   = (u16*)(ws + 32 * MB);      // 16 MB, h then h2
    u16* qbuf   = (u16*)(ws + 48 * MB);      // 16 MB
    u16* kbuf   = (u16*)(ws + 64 * MB);      // 16 MB
    u16* vbuf   = (u16*)(ws + 80 * MB);      // 16 MB
    u16* attnb  = (u16*)(ws + 96 * MB);      // 16 MB
    u16* upbuf  = (u16*)(ws + 48 * MB);      // 64 MB, aliases q/k/v/attn (dead)
    u16* wbufA  = (u16*)(ws + 112 * MB);     // 32 MB: wq / wo / w_up / w_down
    u16* wbufB  = (u16*)(ws + 120 * MB);     // 8 MB: wk
    u16* wbufC  = (u16*)(ws + 128 * MB);     // 8 MB: wv

    dim3 blk(256);
    const int nW = D_ * D_;      // 4M
    const int nU = DFF_ * D_;    // 16M
    cvt_bf16<<<(nW / 4 + 255) / 256, blk, 0, stream>>>(wq, wbufA, nW / 4);
    cvt_bf16<<<(nW / 4 + 255) / 256, blk, 0, stream>>>(wk, wbufB, nW / 4);
    cvt_bf16<<<(nW / 4 + 255) / 256, blk, 0, stream>>>(wv, wbufC, nW / 4);
    rmsnorm_kernel<<<NTOK, blk, 0, stream>>>(x, ln1_w, hbuf);

    dim3 g1(D_ / 128, NTOK / 128);           // (16, 32)
    gemm_bt<0><<<g1, blk, 0, stream>>>(hbuf, wbufA, qbuf, nullptr, NTOK, D_, D_, 0.08838834764831845f);
    gemm_bt<0><<<g1, blk, 0, stream>>>(hbuf, wbufB, kbuf, nullptr, NTOK, D_, D_, 1.0f);
    gemm_bt<0><<<g1, blk, 0, stream>>>(hbuf, wbufC, vbuf, nullptr, NTOK, D_, D_, 1.0f);

    dim3 ga(L_ / 64, B_ * H_);               // (32, 32)
    attn_kernel<<<ga, blk, 0, stream>>>(qbuf, kbuf, vbuf, attnb);

    cvt_bf16<<<(nW / 4 + 255) / 256, blk, 0, stream>>>(wo, wbufA, nW / 4);
    gemm_bt<1><<<g1, blk, 0, stream>>>(attnb, wbufA, x2, x, NTOK, D_, D_, 1.0f);

    rmsnorm_kernel<<<NTOK, blk, 0, stream>>>(x2, ln2_w, hbuf);

    cvt_bf16<<<(nU / 4 + 255) / 256, blk, 0, stream>>>(w_up, wbufA, nU / 4);
    dim3 g2(DFF_ / 128, NTOK / 128);         // (64, 32)
    gemm_bt<2><<<g2, blk, 0, stream>>>(hbuf, wbufA, upbuf, nullptr, NTOK, DFF_, D_, 1.0f);

    cvt_bf16<<<(nU / 4 + 255) / 256, blk, 0, stream>>>(w_dn, wbufA, nU / 4);
    gemm_bt<1><<<g1, blk, 0, stream>>>(upbuf, wbufA, (float*)d_out, x2, NTOK, D_, DFF_, 1.0f);
}

// Round 2
// 955.513 us; speedup vs baseline: 1.4179x; 1.4179x over previous
//
#include <hip/hip_runtime.h>
#include <hip/hip_bf16.h>
#include <math.h>

#define B_   2
#define L_   2048
#define D_   2048
#define H_   16
#define DH_  128
#define DFF_ 8192
#define NTOK (B_*L_)

typedef __attribute__((ext_vector_type(8))) short bf16x8;
typedef __attribute__((ext_vector_type(4))) float floatx4;
typedef unsigned short u16;

__device__ __forceinline__ u16 f2bf(float f) {
    union { float f; unsigned u; } c; c.f = f;
    unsigned r = (c.u + 0x7fffu + ((c.u >> 16) & 1u)) >> 16;
    return (u16)r;
}

__device__ __forceinline__ void async_cp16(const u16* g, u16* l) {
    __builtin_amdgcn_global_load_lds(
        (const __attribute__((address_space(1))) unsigned int*)g,
        (__attribute__((address_space(3))) unsigned int*)l,
        16, 0, 0);
}

// ---------------- fp32 -> bf16 convert ----------------
__global__ __launch_bounds__(256) void cvt_bf16(const float* __restrict__ in,
                                                u16* __restrict__ out, int n4) {
    int i = blockIdx.x * 256 + threadIdx.x;
    if (i >= n4) return;
    float4 v = ((const float4*)in)[i];
    ushort4 o = { f2bf(v.x), f2bf(v.y), f2bf(v.z), f2bf(v.w) };
    ((ushort4*)out)[i] = o;
}

// ---------------- RMSNorm: fp32 in -> bf16 out ----------------
__global__ __launch_bounds__(256) void rmsnorm_kernel(const float* __restrict__ x,
                                                      const float* __restrict__ w,
                                                      u16* __restrict__ out) {
    const int row = blockIdx.x, tid = threadIdx.x;
    const float* xr = x + (size_t)row * D_;
    float4 a = ((const float4*)xr)[tid];
    float4 b = ((const float4*)xr)[tid + 256];
    float ss = a.x*a.x + a.y*a.y + a.z*a.z + a.w*a.w
             + b.x*b.x + b.y*b.y + b.z*b.z + b.w*b.w;
#pragma unroll
    for (int d = 1; d < 64; d <<= 1) ss += __shfl_xor(ss, d, 64);
    __shared__ float sred[4];
    if ((tid & 63) == 0) sred[tid >> 6] = ss;
    __syncthreads();
    float tot = sred[0] + sred[1] + sred[2] + sred[3];
    float inv = 1.0f / sqrtf(tot * (1.0f / D_) + 1e-8f);
    float4 w0 = ((const float4*)w)[tid];
    float4 w1 = ((const float4*)w)[tid + 256];
    ushort4 o0 = { f2bf(a.x*inv*w0.x), f2bf(a.y*inv*w0.y), f2bf(a.z*inv*w0.z), f2bf(a.w*inv*w0.w) };
    ushort4 o1 = { f2bf(b.x*inv*w1.x), f2bf(b.y*inv*w1.y), f2bf(b.z*inv*w1.z), f2bf(b.w*inv*w1.w) };
    ushort4* orow = (ushort4*)(out + (size_t)row * D_);
    orow[tid] = o0;
    orow[tid + 256] = o1;
}

// ---------------- GEMM: C[M,N] = A[M,K] * W[N,K]^T, bf16 in, fp32 acc ----------------
// MODE 0: out bf16 in [B,H,L,DH] layout, scaled (Q/K projections)
// MODE 1: out fp32 = acc + residual[m*N+n]
// MODE 2: out bf16 row-major with exact-erf GELU applied
// MODE 3: out bf16 row-major plain (used for V^T via swapped operands)
template<int MODE>
__global__ __launch_bounds__(256) void gemm_bt(const u16* __restrict__ A,
                                               const u16* __restrict__ Bw,
                                               void* __restrict__ outp,
                                               const float* __restrict__ residual,
                                               int M, int N, int K, float scale) {
    __shared__ __attribute__((aligned(16))) u16 lds_a[128 * 32];
    __shared__ __attribute__((aligned(16))) u16 lds_b[128 * 32];
    const int tid = threadIdx.x;
    const int wave = tid >> 6, lane = tid & 63;
    const int qd = lane >> 4, c16 = lane & 15;
    const int wm = (wave >> 1) * 64, wn = (wave & 1) * 64;
    const long tile_m = (long)blockIdx.y * 128, tile_n = (long)blockIdx.x * 128;

    floatx4 acc[4][4] = {};

    const int r0 = tid >> 2;            // 0..63
    const int r1 = r0 + 64;             // 64..127
    const int kc = (tid & 3) * 8;       // 0,8,16,24
    const u16* a0 = A + (tile_m + r0) * (long)K + kc;
    const u16* a1 = A + (tile_m + r1) * (long)K + kc;
    const u16* b0 = Bw + (tile_n + r0) * (long)K + kc;
    const u16* b1 = Bw + (tile_n + r1) * (long)K + kc;

    for (int k0 = 0; k0 < K; k0 += 32) {
        async_cp16(a0 + k0, &lds_a[r0 * 32 + kc]);
        async_cp16(a1 + k0, &lds_a[r1 * 32 + kc]);
        async_cp16(b0 + k0, &lds_b[r0 * 32 + kc]);
        async_cp16(b1 + k0, &lds_b[r1 * 32 + kc]);
        __syncthreads();
        bf16x8 af[4], bv[4];
#pragma unroll
        for (int i = 0; i < 4; i++)
            af[i] = *(const bf16x8*)&lds_a[(wm + i * 16 + c16) * 32 + qd * 8];
#pragma unroll
        for (int j = 0; j < 4; j++)
            bv[j] = *(const bf16x8*)&lds_b[(wn + j * 16 + c16) * 32 + qd * 8];
#pragma unroll
        for (int i = 0; i < 4; i++)
#pragma unroll
            for (int j = 0; j < 4; j++)
                acc[i][j] = __builtin_amdgcn_mfma_f32_16x16x32_bf16(af[i], bv[j], acc[i][j], 0, 0, 0);
        __syncthreads();
    }

#pragma unroll
    for (int i = 0; i < 4; i++) {
#pragma unroll
        for (int j = 0; j < 4; j++) {
#pragma unroll
            for (int r = 0; r < 4; r++) {
                long m = tile_m + wm + i * 16 + qd * 4 + r;
                long n = tile_n + wn + j * 16 + c16;
                float v = acc[i][j][r];
                if (MODE == 0) {
                    long b = m >> 11, l = m & 2047;   // L_ = 2048
                    long h = n >> 7, dh = n & 127;    // DH_ = 128
                    ((u16*)outp)[((b * H_ + h) * (long)L_ + l) * DH_ + dh] = f2bf(v * scale);
                } else if (MODE == 1) {
                    long idx = m * (long)N + n;
                    ((float*)outp)[idx] = v + residual[idx];
                } else if (MODE == 2) {
                    float g = 0.5f * v * (1.0f + erff(v * 0.70710678118654752f));
                    ((u16*)outp)[m * (long)N + n] = f2bf(g);
                } else {
                    ((u16*)outp)[m * (long)N + n] = f2bf(v);
                }
            }
        }
    }
}

// ---------------- Flash-style causal attention ----------------
// grid: (16 q-tile pairs, B*H heads). Block p handles q-tiles {p, 31-p}
// (uniform 33 kv-tile iterations per block). 4 waves, 16 Q rows per wave.
// V comes PRE-TRANSPOSED: VT[vfeat][token], vfeat = h*DH+dh, token = b*L+l.
#define KSTRIDE 136   // 64x128 K tile, padded
#define VSTRIDE 72    // 128x64 V^T tile, padded
#define PSTRIDE 72    // 16x64 per-wave P tile, padded
__global__ __launch_bounds__(256) void attn_kernel(const u16* __restrict__ Q,
                                                   const u16* __restrict__ K,
                                                   const u16* __restrict__ VT,
                                                   u16* __restrict__ O) {
    __shared__ __attribute__((aligned(16))) u16 kt_lds[64 * KSTRIDE];
    __shared__ __attribute__((aligned(16))) u16 vt_lds[128 * VSTRIDE];
    __shared__ __attribute__((aligned(16))) u16 p_lds[4][16 * PSTRIDE];
    const int tid = threadIdx.x;
    const int wave = tid >> 6, lane = tid & 63;
    const int qd = lane >> 4, c16 = lane & 15;
    const int pair = blockIdx.x, bh = blockIdx.y;
    const int b = bh >> 4, h = bh & 15;
    const u16* qh = Q + (size_t)bh * L_ * DH_;
    const u16* kh = K + (size_t)bh * L_ * DH_;
    const u16* vth = VT + (size_t)h * DH_ * NTOK + (size_t)b * L_;

    for (int qsel = 0; qsel < 2; ++qsel) {
        const int qt = qsel ? (31 - pair) : pair;
        const int q0 = qt * 64;

        bf16x8 qf[4];
#pragma unroll
        for (int s = 0; s < 4; s++)
            qf[s] = *(const bf16x8*)(qh + (size_t)(q0 + wave * 16 + c16) * DH_ + s * 32 + qd * 8);

        floatx4 o_acc[8] = {};
        float m_i[4], l_i[4];
#pragma unroll
        for (int r = 0; r < 4; r++) { m_i[r] = -1e30f; l_i[r] = 0.f; }

        for (int kt = 0; kt <= qt; kt++) {
            const int kv0 = kt * 64;
            // stage K tile [64 kv][128 dh] and V^T tile [128 dh][64 kv]
#pragma unroll
            for (int s = 0; s < 4; s++) {
                int c = tid + s * 256;
                int kr = c >> 4, koff = (c & 15) * 8;
                *(int4*)&kt_lds[kr * KSTRIDE + koff] =
                    *(const int4*)(kh + (size_t)(kv0 + kr) * DH_ + koff);
                int dh = c >> 3, kv8 = (c & 7) * 8;
                *(int4*)&vt_lds[dh * VSTRIDE + kv8] =
                    *(const int4*)(vth + (size_t)dh * NTOK + kv0 + kv8);
            }
            __syncthreads();

            // S = Q K^T  (A=Q frags, B=K rows)
            floatx4 s_acc[4] = {};
#pragma unroll
            for (int j = 0; j < 4; j++)
#pragma unroll
                for (int s = 0; s < 4; s++) {
                    bf16x8 kf = *(const bf16x8*)&kt_lds[(j * 16 + c16) * KSTRIDE + s * 32 + qd * 8];
                    s_acc[j] = __builtin_amdgcn_mfma_f32_16x16x32_bf16(qf[s], kf, s_acc[j], 0, 0, 0);
                }

            if (kt == qt) {
#pragma unroll
                for (int j = 0; j < 4; j++)
#pragma unroll
                    for (int r = 0; r < 4; r++) {
                        int col = j * 16 + c16;
                        int row = wave * 16 + qd * 4 + r;
                        if (col > row) s_acc[j][r] = -1e30f;
                    }
            }

            float rsum[4], alpha[4];
#pragma unroll
            for (int r = 0; r < 4; r++) {
                float mx = fmaxf(fmaxf(s_acc[0][r], s_acc[1][r]), fmaxf(s_acc[2][r], s_acc[3][r]));
#pragma unroll
                for (int d = 1; d < 16; d <<= 1) mx = fmaxf(mx, __shfl_xor(mx, d, 64));
                float mnew = fmaxf(m_i[r], mx);
                alpha[r] = __expf(m_i[r] - mnew);
                m_i[r] = mnew;
                rsum[r] = 0.f;
            }
#pragma unroll
            for (int j = 0; j < 4; j++)
#pragma unroll
                for (int r = 0; r < 4; r++) {
                    float p = __expf(s_acc[j][r] - m_i[r]);
                    s_acc[j][r] = p;
                    rsum[r] += p;
                }
#pragma unroll
            for (int r = 0; r < 4; r++) {
#pragma unroll
                for (int d = 1; d < 16; d <<= 1) rsum[r] += __shfl_xor(rsum[r], d, 64);
                l_i[r] = l_i[r] * alpha[r] + rsum[r];
            }
#pragma unroll
            for (int j8 = 0; j8 < 8; j8++)
#pragma unroll
                for (int r = 0; r < 4; r++) o_acc[j8][r] *= alpha[r];

            // P: C-layout -> LDS (padded) -> A-layout, per-wave region
#pragma unroll
            for (int j = 0; j < 4; j++)
#pragma unroll
                for (int r = 0; r < 4; r++)
                    p_lds[wave][(qd * 4 + r) * PSTRIDE + j * 16 + c16] = f2bf(s_acc[j][r]);

#pragma unroll
            for (int s = 0; s < 2; s++) {
                bf16x8 pf = *(const bf16x8*)&p_lds[wave][c16 * PSTRIDE + s * 32 + qd * 8];
#pragma unroll
                for (int j8 = 0; j8 < 8; j8++) {
                    bf16x8 vf = *(const bf16x8*)&vt_lds[(j8 * 16 + c16) * VSTRIDE + s * 32 + qd * 8];
                    o_acc[j8] = __builtin_amdgcn_mfma_f32_16x16x32_bf16(pf, vf, o_acc[j8], 0, 0, 0);
                }
            }
            __syncthreads();
        }

        float inv_l[4];
#pragma unroll
        for (int r = 0; r < 4; r++) inv_l[r] = 1.0f / l_i[r];
#pragma unroll
        for (int j8 = 0; j8 < 8; j8++)
#pragma unroll
            for (int r = 0; r < 4; r++) {
                int l = q0 + wave * 16 + qd * 4 + r;
                int d = h * DH_ + j8 * 16 + c16;
                O[(size_t)(b * L_ + l) * D_ + d] = f2bf(o_acc[j8][r] * inv_l[r]);
            }
    }
}

// ---------------- launch ----------------
extern "C" void kernel_launch(void* const* d_in, const int* in_sizes, int n_in,
                              void* d_out, int out_size, void* d_ws, size_t ws_size,
                              hipStream_t stream) {
    const float* x     = (const float*)d_in[0];
    const float* ln1_w = (const float*)d_in[2];
    const float* wq    = (const float*)d_in[3];
    const float* wk    = (const float*)d_in[4];
    const float* wv    = (const float*)d_in[5];
    const float* wo    = (const float*)d_in[6];
    const float* ln2_w = (const float*)d_in[7];
    const float* w_up  = (const float*)d_in[8];
    const float* w_dn  = (const float*)d_in[9];

    char* ws = (char*)d_ws;
    const size_t MB = 1024 * 1024;
    float* x2   = (float*)(ws + 0);          // 32 MB, live to end
    u16* hbuf   = (u16*)(ws + 32 * MB);      // 16 MB, h then h2
    u16* qbuf   = (u16*)(ws + 48 * MB);      // 16 MB
    u16* kbuf   = (u16*)(ws + 64 * MB);      // 16 MB
    u16* vtbuf  = (u16*)(ws + 80 * MB);      // 16 MB  V^T [D][NTOK]
    u16* attnb  = (u16*)(ws + 96 * MB);      // 16 MB
    u16* upbuf  = (u16*)(ws + 48 * MB);      // 64 MB, aliases q/k/vt/attn (dead)
    u16* wbufA  = (u16*)(ws + 112 * MB);     // wq / wo / w_up / w_down
    u16* wbufB  = (u16*)(ws + 120 * MB);     // wk
    u16* wbufC  = (u16*)(ws + 128 * MB);     // wv

    dim3 blk(256);
    const int nW = D_ * D_;      // 4M
    const int nU = DFF_ * D_;    // 16M
    cvt_bf16<<<(nW / 4 + 255) / 256, blk, 0, stream>>>(wq, wbufA, nW / 4);
    cvt_bf16<<<(nW / 4 + 255) / 256, blk, 0, stream>>>(wk, wbufB, nW / 4);
    cvt_bf16<<<(nW / 4 + 255) / 256, blk, 0, stream>>>(wv, wbufC, nW / 4);
    rmsnorm_kernel<<<NTOK, blk, 0, stream>>>(x, ln1_w, hbuf);

    dim3 g1(D_ / 128, NTOK / 128);           // (16, 32)
    gemm_bt<0><<<g1, blk, 0, stream>>>(hbuf, wbufA, qbuf, nullptr, NTOK, D_, D_, 0.08838834764831845f);
    gemm_bt<0><<<g1, blk, 0, stream>>>(hbuf, wbufB, kbuf, nullptr, NTOK, D_, D_, 1.0f);
    // V^T = Wv @ h^T : swapped operands, output [vfeat][token] row-major
    dim3 gv(NTOK / 128, D_ / 128);           // (32, 16)
    gemm_bt<3><<<gv, blk, 0, stream>>>(wbufC, hbuf, vtbuf, nullptr, D_, NTOK, D_, 1.0f);

    dim3 ga(16, B_ * H_);                    // paired q-tiles x heads
    attn_kernel<<<ga, blk, 0, stream>>>(qbuf, kbuf, vtbuf, attnb);

    cvt_bf16<<<(nW / 4 + 255) / 256, blk, 0, stream>>>(wo, wbufA, nW / 4);
    gemm_bt<1><<<g1, blk, 0, stream>>>(attnb, wbufA, x2, x, NTOK, D_, D_, 1.0f);

    rmsnorm_kernel<<<NTOK, blk, 0, stream>>>(x2, ln2_w, hbuf);

    cvt_bf16<<<(nU / 4 + 255) / 256, blk, 0, stream>>>(w_up, wbufA, nU / 4);
    dim3 g2(DFF_ / 128, NTOK / 128);         // (64, 32)
    gemm_bt<2><<<g2, blk, 0, stream>>>(hbuf, wbufA, upbuf, nullptr, NTOK, DFF_, D_, 1.0f);

    cvt_bf16<<<(nU / 4 + 255) / 256, blk, 0, stream>>>(w_dn, wbufA, nU / 4);
    gemm_bt<1><<<g1, blk, 0, stream>>>(upbuf, wbufA, (float*)d_out, x2, NTOK, D_, DFF_, 1.0f);
}

// Round 3
// 873.468 us; speedup vs baseline: 1.5511x; 1.0939x over previous
//
#include <hip/hip_runtime.h>
#include <hip/hip_bf16.h>
#include <math.h>

#define B_   2
#define L_   2048
#define D_   2048
#define H_   16
#define DH_  128
#define DFF_ 8192
#define NTOK (B_*L_)

typedef __attribute__((ext_vector_type(8))) short bf16x8;
typedef __attribute__((ext_vector_type(4))) float floatx4;
typedef unsigned short u16;

__device__ __forceinline__ u16 f2bf(float f) {
    union { float f; unsigned u; } c; c.f = f;
    unsigned r = (c.u + 0x7fffu + ((c.u >> 16) & 1u)) >> 16;
    return (u16)r;
}

__device__ __forceinline__ void async_cp16(const u16* g, u16* l) {
    __builtin_amdgcn_global_load_lds(
        (const __attribute__((address_space(1))) unsigned int*)g,
        (__attribute__((address_space(3))) unsigned int*)l,
        16, 0, 0);
}

// ---------------- fp32 -> bf16 convert ----------------
__global__ __launch_bounds__(256) void cvt_bf16(const float* __restrict__ in,
                                                u16* __restrict__ out, int n4) {
    int i = blockIdx.x * 256 + threadIdx.x;
    if (i >= n4) return;
    float4 v = ((const float4*)in)[i];
    ushort4 o = { f2bf(v.x), f2bf(v.y), f2bf(v.z), f2bf(v.w) };
    ((ushort4*)out)[i] = o;
}

// ---------------- RMSNorm: fp32 in -> bf16 out ----------------
__global__ __launch_bounds__(256) void rmsnorm_kernel(const float* __restrict__ x,
                                                      const float* __restrict__ w,
                                                      u16* __restrict__ out) {
    const int row = blockIdx.x, tid = threadIdx.x;
    const float* xr = x + (size_t)row * D_;
    float4 a = ((const float4*)xr)[tid];
    float4 b = ((const float4*)xr)[tid + 256];
    float ss = a.x*a.x + a.y*a.y + a.z*a.z + a.w*a.w
             + b.x*b.x + b.y*b.y + b.z*b.z + b.w*b.w;
#pragma unroll
    for (int d = 1; d < 64; d <<= 1) ss += __shfl_xor(ss, d, 64);
    __shared__ float sred[4];
    if ((tid & 63) == 0) sred[tid >> 6] = ss;
    __syncthreads();
    float tot = sred[0] + sred[1] + sred[2] + sred[3];
    float inv = 1.0f / sqrtf(tot * (1.0f / D_) + 1e-8f);
    float4 w0 = ((const float4*)w)[tid];
    float4 w1 = ((const float4*)w)[tid + 256];
    ushort4 o0 = { f2bf(a.x*inv*w0.x), f2bf(a.y*inv*w0.y), f2bf(a.z*inv*w0.z), f2bf(a.w*inv*w0.w) };
    ushort4 o1 = { f2bf(b.x*inv*w1.x), f2bf(b.y*inv*w1.y), f2bf(b.z*inv*w1.z), f2bf(b.w*inv*w1.w) };
    ushort4* orow = (ushort4*)(out + (size_t)row * D_);
    orow[tid] = o0;
    orow[tid + 256] = o1;
}

// ---------------- GEMM: C[M,N] = A[M,K] * W[N,K]^T, bf16 in, fp32 acc ----------------
// Two BK=32 panels per barrier (halves barrier-drain count; per-panel LDS layout
// keeps the m97-proven banking AND the global_load_lds lane-contiguity rule).
// MODE 0: fused Q/K projection: n<2048 -> outp (Q, scaled), else outp2 (K),
//         both stored as [B,H,L,DH]
// MODE 1: out fp32 = acc + residual[m*N+n]
// MODE 2: out bf16 row-major with exact-erf GELU
// MODE 3: out bf16 row-major plain (V^T via swapped operands)
template<int MODE>
__global__ __launch_bounds__(256) void gemm_bt(const u16* __restrict__ A,
                                               const u16* __restrict__ Bw,
                                               void* __restrict__ outp,
                                               void* __restrict__ outp2,
                                               const float* __restrict__ residual,
                                               int M, int N, int K, float scale) {
    __shared__ __attribute__((aligned(16))) u16 lds_a[2][128 * 32];
    __shared__ __attribute__((aligned(16))) u16 lds_b[2][128 * 32];
    const int tid = threadIdx.x;
    const int wave = tid >> 6, lane = tid & 63;
    const int qd = lane >> 4, c16 = lane & 15;
    const int wm = (wave >> 1) * 64, wn = (wave & 1) * 64;
    const long tile_m = (long)blockIdx.y * 128, tile_n = (long)blockIdx.x * 128;

    floatx4 acc[4][4] = {};

    const int r0 = tid >> 2;            // 0..63
    const int r1 = r0 + 64;             // 64..127
    const int kc = (tid & 3) * 8;       // 0,8,16,24
    const u16* a0 = A + (tile_m + r0) * (long)K + kc;
    const u16* a1 = A + (tile_m + r1) * (long)K + kc;
    const u16* b0 = Bw + (tile_n + r0) * (long)K + kc;
    const u16* b1 = Bw + (tile_n + r1) * (long)K + kc;

    for (int k0 = 0; k0 < K; k0 += 64) {
#pragma unroll
        for (int p = 0; p < 2; p++) {
            const int kp = k0 + p * 32;
            async_cp16(a0 + kp, &lds_a[p][r0 * 32 + kc]);
            async_cp16(a1 + kp, &lds_a[p][r1 * 32 + kc]);
            async_cp16(b0 + kp, &lds_b[p][r0 * 32 + kc]);
            async_cp16(b1 + kp, &lds_b[p][r1 * 32 + kc]);
        }
        __syncthreads();
#pragma unroll
        for (int p = 0; p < 2; p++) {
            bf16x8 af[4], bv[4];
#pragma unroll
            for (int i = 0; i < 4; i++)
                af[i] = *(const bf16x8*)&lds_a[p][(wm + i * 16 + c16) * 32 + qd * 8];
#pragma unroll
            for (int j = 0; j < 4; j++)
                bv[j] = *(const bf16x8*)&lds_b[p][(wn + j * 16 + c16) * 32 + qd * 8];
#pragma unroll
            for (int i = 0; i < 4; i++)
#pragma unroll
                for (int j = 0; j < 4; j++)
                    acc[i][j] = __builtin_amdgcn_mfma_f32_16x16x32_bf16(af[i], bv[j], acc[i][j], 0, 0, 0);
        }
        __syncthreads();
    }

#pragma unroll
    for (int i = 0; i < 4; i++) {
#pragma unroll
        for (int j = 0; j < 4; j++) {
#pragma unroll
            for (int r = 0; r < 4; r++) {
                long m = tile_m + wm + i * 16 + qd * 4 + r;
                long n = tile_n + wn + j * 16 + c16;
                float v = acc[i][j][r];
                if (MODE == 0) {
                    long b = m >> 11, l = m & 2047;   // L_ = 2048
                    int isq = n < D_;
                    long f = n & 2047, h = f >> 7, dh = f & 127;
                    u16* dst = isq ? (u16*)outp : (u16*)outp2;
                    dst[((b * H_ + h) * (long)L_ + l) * DH_ + dh] =
                        f2bf(v * (isq ? scale : 1.0f));
                } else if (MODE == 1) {
                    long idx = m * (long)N + n;
                    ((float*)outp)[idx] = v + residual[idx];
                } else if (MODE == 2) {
                    float g = 0.5f * v * (1.0f + erff(v * 0.70710678118654752f));
                    ((u16*)outp)[m * (long)N + n] = f2bf(g);
                } else {
                    ((u16*)outp)[m * (long)N + n] = f2bf(v);
                }
            }
        }
    }
}

// ---------------- Flash-style causal attention ----------------
// grid: (16 q-tile pairs, B*H heads). Block p handles q-tiles {p, 31-p}
// (uniform 33 kv-tile iterations per block). 4 waves, 16 Q rows per wave.
// V comes PRE-TRANSPOSED: VT[vfeat][token], vfeat = h*DH+dh, token = b*L+l.
#define KSTRIDE 136   // 64x128 K tile, padded
#define VSTRIDE 72    // 128x64 V^T tile, padded
#define PSTRIDE 72    // 16x64 per-wave P tile, padded
__global__ __launch_bounds__(256) void attn_kernel(const u16* __restrict__ Q,
                                                   const u16* __restrict__ K,
                                                   const u16* __restrict__ VT,
                                                   u16* __restrict__ O) {
    __shared__ __attribute__((aligned(16))) u16 kt_lds[64 * KSTRIDE];
    __shared__ __attribute__((aligned(16))) u16 vt_lds[128 * VSTRIDE];
    __shared__ __attribute__((aligned(16))) u16 p_lds[4][16 * PSTRIDE];
    const int tid = threadIdx.x;
    const int wave = tid >> 6, lane = tid & 63;
    const int qd = lane >> 4, c16 = lane & 15;
    const int pair = blockIdx.x, bh = blockIdx.y;
    const int b = bh >> 4, h = bh & 15;
    const u16* qh = Q + (size_t)bh * L_ * DH_;
    const u16* kh = K + (size_t)bh * L_ * DH_;
    const u16* vth = VT + (size_t)h * DH_ * NTOK + (size_t)b * L_;

    for (int qsel = 0; qsel < 2; ++qsel) {
        const int qt = qsel ? (31 - pair) : pair;
        const int q0 = qt * 64;

        bf16x8 qf[4];
#pragma unroll
        for (int s = 0; s < 4; s++)
            qf[s] = *(const bf16x8*)(qh + (size_t)(q0 + wave * 16 + c16) * DH_ + s * 32 + qd * 8);

        floatx4 o_acc[8] = {};
        float m_i[4], l_i[4];
#pragma unroll
        for (int r = 0; r < 4; r++) { m_i[r] = -1e30f; l_i[r] = 0.f; }

        for (int kt = 0; kt <= qt; kt++) {
            const int kv0 = kt * 64;
#pragma unroll
            for (int s = 0; s < 4; s++) {
                int c = tid + s * 256;
                int kr = c >> 4, koff = (c & 15) * 8;
                *(int4*)&kt_lds[kr * KSTRIDE + koff] =
                    *(const int4*)(kh + (size_t)(kv0 + kr) * DH_ + koff);
                int dh = c >> 3, kv8 = (c & 7) * 8;
                *(int4*)&vt_lds[dh * VSTRIDE + kv8] =
                    *(const int4*)(vth + (size_t)dh * NTOK + kv0 + kv8);
            }
            __syncthreads();

            floatx4 s_acc[4] = {};
#pragma unroll
            for (int j = 0; j < 4; j++)
#pragma unroll
                for (int s = 0; s < 4; s++) {
                    bf16x8 kf = *(const bf16x8*)&kt_lds[(j * 16 + c16) * KSTRIDE + s * 32 + qd * 8];
                    s_acc[j] = __builtin_amdgcn_mfma_f32_16x16x32_bf16(qf[s], kf, s_acc[j], 0, 0, 0);
                }

            if (kt == qt) {
#pragma unroll
                for (int j = 0; j < 4; j++)
#pragma unroll
                    for (int r = 0; r < 4; r++) {
                        int col = j * 16 + c16;
                        int row = wave * 16 + qd * 4 + r;
                        if (col > row) s_acc[j][r] = -1e30f;
                    }
            }

            float rsum[4], alpha[4];
#pragma unroll
            for (int r = 0; r < 4; r++) {
                float mx = fmaxf(fmaxf(s_acc[0][r], s_acc[1][r]), fmaxf(s_acc[2][r], s_acc[3][r]));
#pragma unroll
                for (int d = 1; d < 16; d <<= 1) mx = fmaxf(mx, __shfl_xor(mx, d, 64));
                float mnew = fmaxf(m_i[r], mx);
                alpha[r] = __expf(m_i[r] - mnew);
                m_i[r] = mnew;
                rsum[r] = 0.f;
            }
#pragma unroll
            for (int j = 0; j < 4; j++)
#pragma unroll
                for (int r = 0; r < 4; r++) {
                    float p = __expf(s_acc[j][r] - m_i[r]);
                    s_acc[j][r] = p;
                    rsum[r] += p;
                }
#pragma unroll
            for (int r = 0; r < 4; r++) {
#pragma unroll
                for (int d = 1; d < 16; d <<= 1) rsum[r] += __shfl_xor(rsum[r], d, 64);
                l_i[r] = l_i[r] * alpha[r] + rsum[r];
            }
#pragma unroll
            for (int j8 = 0; j8 < 8; j8++)
#pragma unroll
                for (int r = 0; r < 4; r++) o_acc[j8][r] *= alpha[r];

#pragma unroll
            for (int j = 0; j < 4; j++)
#pragma unroll
                for (int r = 0; r < 4; r++)
                    p_lds[wave][(qd * 4 + r) * PSTRIDE + j * 16 + c16] = f2bf(s_acc[j][r]);

#pragma unroll
            for (int s = 0; s < 2; s++) {
                bf16x8 pf = *(const bf16x8*)&p_lds[wave][c16 * PSTRIDE + s * 32 + qd * 8];
#pragma unroll
                for (int j8 = 0; j8 < 8; j8++) {
                    bf16x8 vf = *(const bf16x8*)&vt_lds[(j8 * 16 + c16) * VSTRIDE + s * 32 + qd * 8];
                    o_acc[j8] = __builtin_amdgcn_mfma_f32_16x16x32_bf16(pf, vf, o_acc[j8], 0, 0, 0);
                }
            }
            __syncthreads();
        }

        float inv_l[4];
#pragma unroll
        for (int r = 0; r < 4; r++) inv_l[r] = 1.0f / l_i[r];
#pragma unroll
        for (int j8 = 0; j8 < 8; j8++)
#pragma unroll
            for (int r = 0; r < 4; r++) {
                int l = q0 + wave * 16 + qd * 4 + r;
                int d = h * DH_ + j8 * 16 + c16;
                O[(size_t)(b * L_ + l) * D_ + d] = f2bf(o_acc[j8][r] * inv_l[r]);
            }
    }
}

// ---------------- launch ----------------
extern "C" void kernel_launch(void* const* d_in, const int* in_sizes, int n_in,
                              void* d_out, int out_size, void* d_ws, size_t ws_size,
                              hipStream_t stream) {
    const float* x     = (const float*)d_in[0];
    const float* ln1_w = (const float*)d_in[2];
    const float* wq    = (const float*)d_in[3];
    const float* wk    = (const float*)d_in[4];
    const float* wv    = (const float*)d_in[5];
    const float* wo    = (const float*)d_in[6];
    const float* ln2_w = (const float*)d_in[7];
    const float* w_up  = (const float*)d_in[8];
    const float* w_dn  = (const float*)d_in[9];

    char* ws = (char*)d_ws;
    const size_t MB = 1024 * 1024;
    float* x2   = (float*)(ws + 0);          // 32 MB, live to end
    u16* hbuf   = (u16*)(ws + 32 * MB);      // 16 MB, h then h2
    u16* qbuf   = (u16*)(ws + 48 * MB);      // 16 MB
    u16* kbuf   = (u16*)(ws + 64 * MB);      // 16 MB
    u16* vtbuf  = (u16*)(ws + 80 * MB);      // 16 MB  V^T [D][NTOK]
    u16* attnb  = (u16*)(ws + 96 * MB);      // 16 MB
    u16* upbuf  = (u16*)(ws + 48 * MB);      // 64 MB, aliases q/k/vt/attn (dead)
    u16* wbufA  = (u16*)(ws + 112 * MB);     // 32 MB: wq+wk fused / wo / w_up / w_down
    u16* wbufC  = (u16*)(ws + 128 * MB);     // 8 MB: wv

    dim3 blk(256);
    const int nW = D_ * D_;      // 4M
    const int nU = DFF_ * D_;    // 16M
    // fused QK weight: [wq ; wk] = [2D, D]
    cvt_bf16<<<(nW / 4 + 255) / 256, blk, 0, stream>>>(wq, wbufA, nW / 4);
    cvt_bf16<<<(nW / 4 + 255) / 256, blk, 0, stream>>>(wk, wbufA + (size_t)nW, nW / 4);
    cvt_bf16<<<(nW / 4 + 255) / 256, blk, 0, stream>>>(wv, wbufC, nW / 4);
    rmsnorm_kernel<<<NTOK, blk, 0, stream>>>(x, ln1_w, hbuf);

    // fused Q+K projection: N = 2*D
    dim3 gqk(2 * D_ / 128, NTOK / 128);      // (32, 32)
    gemm_bt<0><<<gqk, blk, 0, stream>>>(hbuf, wbufA, qbuf, kbuf, nullptr,
                                        NTOK, 2 * D_, D_, 0.08838834764831845f);
    // V^T = Wv @ h^T : swapped operands, output [vfeat][token] row-major
    dim3 gv(NTOK / 128, D_ / 128);           // (32, 16)
    gemm_bt<3><<<gv, blk, 0, stream>>>(wbufC, hbuf, vtbuf, nullptr, nullptr, D_, NTOK, D_, 1.0f);

    dim3 ga(16, B_ * H_);                    // paired q-tiles x heads
    attn_kernel<<<ga, blk, 0, stream>>>(qbuf, kbuf, vtbuf, attnb);

    cvt_bf16<<<(nW / 4 + 255) / 256, blk, 0, stream>>>(wo, wbufA, nW / 4);
    dim3 g1(D_ / 128, NTOK / 128);           // (16, 32)
    gemm_bt<1><<<g1, blk, 0, stream>>>(attnb, wbufA, x2, nullptr, x, NTOK, D_, D_, 1.0f);

    rmsnorm_kernel<<<NTOK, blk, 0, stream>>>(x2, ln2_w, hbuf);

    cvt_bf16<<<(nU / 4 + 255) / 256, blk, 0, stream>>>(w_up, wbufA, nU / 4);
    dim3 g2(DFF_ / 128, NTOK / 128);         // (64, 32)
    gemm_bt<2><<<g2, blk, 0, stream>>>(hbuf, wbufA, upbuf, nullptr, nullptr, NTOK, DFF_, D_, 1.0f);

    cvt_bf16<<<(nU / 4 + 255) / 256, blk, 0, stream>>>(w_dn, wbufA, nU / 4);
    gemm_bt<1><<<g1, blk, 0, stream>>>(upbuf, wbufA, (float*)d_out, nullptr, x2, NTOK, D_, DFF_, 1.0f);
}